// Round 5
// baseline (582.762 us; speedup 1.0000x reference)
//
#include <hip/hip_runtime.h>
#include <cstdint>
#include <cstddef>

typedef short short8 __attribute__((ext_vector_type(8)));
typedef short s16x4 __attribute__((ext_vector_type(4)));
typedef float f32x4 __attribute__((ext_vector_type(4)));

typedef const __attribute__((address_space(1))) void* gas_ptr;
typedef __attribute__((address_space(3))) void* las_ptr;

__device__ __forceinline__ unsigned short f2bf(float f) {
    unsigned int u = __float_as_uint(f);
    u += 0x7fffu + ((u >> 16) & 1u);          // RNE (finite inputs)
    return (unsigned short)(u >> 16);
}
__device__ __forceinline__ float bf2f(unsigned short s) {
    return __uint_as_float(((unsigned int)s) << 16);
}
__device__ __forceinline__ float sigmoid_f(float z) {
    return __builtin_amdgcn_rcpf(1.0f + __expf(-z));
}
__device__ __forceinline__ void async_copy16(const void* gp, void* lp) {
    __builtin_amdgcn_global_load_lds((gas_ptr)gp, (las_ptr)lp, 16, 0, 0);
}

// ---------------- converters ----------------
// x: [32768,1024] f32 -> bf16, same layout. 8 elems/thread.
__global__ __launch_bounds__(256) void cvt_x_kernel(const float* __restrict__ in,
                                                    unsigned short* __restrict__ out) {
    size_t i = ((size_t)blockIdx.x * 256 + threadIdx.x) * 8;
    float4 v0 = *(const float4*)(in + i);
    float4 v1 = *(const float4*)(in + i + 4);
    short8 o;
    o[0]=(short)f2bf(v0.x); o[1]=(short)f2bf(v0.y); o[2]=(short)f2bf(v0.z); o[3]=(short)f2bf(v0.w);
    o[4]=(short)f2bf(v1.x); o[5]=(short)f2bf(v1.y); o[6]=(short)f2bf(v1.z); o[7]=(short)f2bf(v1.w);
    *(short8*)(out + i) = o;
}

// W: [1024,4096] f32 -> W_T bf16 [4096,1024]. 64x64 LDS tiles.
__global__ __launch_bounds__(256) void cvt_w_kernel(const float* __restrict__ W,
                                                    unsigned short* __restrict__ Wt) {
    __shared__ unsigned short tile[64][65];
    int bk = blockIdx.x >> 6, bn = blockIdx.x & 63;
    int k0 = bk * 64, n0 = bn * 64;
    int t = threadIdx.x;
    int cr = t >> 6;          // 0..3
    int cc = t & 63;          // 0..63
#pragma unroll
    for (int i = 0; i < 16; ++i) {
        int row = i * 4 + cr;
        tile[row][cc] = f2bf(W[(size_t)(k0 + row) * 4096 + n0 + cc]);
    }
    __syncthreads();
#pragma unroll
    for (int i = 0; i < 16; ++i) {
        int nrow = i * 4 + cr;
        Wt[(size_t)(n0 + nrow) * 1024 + k0 + cc] = tile[cc][nrow];
    }
}

// ---------------- GEMM ----------------
// (unchanged — 251-256 us, MfmaUtil 52%)
// Output: gT bf16 TIME-MAJOR blocked [T/8][b][gate][u][8].
__global__ __launch_bounds__(256, 2) void gemm_kernel(const unsigned short* __restrict__ A,
                                                      const unsigned short* __restrict__ Bt,
                                                      const float* __restrict__ bias,
                                                      unsigned short* __restrict__ gT) {
    __shared__ __align__(16) unsigned short As[128 * 64];
    __shared__ __align__(16) unsigned short Bs[128 * 64];

    // band swizzle: 8 m-tiles x 32 n-tiles per band, n fastest
    int bid = blockIdx.x;
    int band = bid >> 8;
    int r = bid & 255;
    int mt = band * 8 + (r >> 5);
    int nt = r & 31;
    int m0 = mt * 128, n0 = nt * 128;

    int tidx = threadIdx.x;
    int lane = tidx & 63, wv = tidx >> 6;
    int wm = wv >> 1, wn = wv & 1;
    int l15 = lane & 15, quad = lane >> 4;

    f32x4 acc[4][4] = {};

    for (int k0 = 0; k0 < 1024; k0 += 64) {
        __syncthreads();
#pragma unroll
        for (int i = 0; i < 4; ++i) {
            int ci = (wv * 4 + i) * 64 + lane;      // 0..1023
            int row = ci >> 3, cc = ci & 7;
            int sc = (cc ^ (row & 7)) << 3;         // swizzled k-offset (elements)
            const unsigned short* ga = A + (size_t)(m0 + row) * 1024 + k0 + sc;
            async_copy16(ga, (char*)As + (wv * 4 + i) * 1024);
            const unsigned short* gb = Bt + (size_t)(n0 + row) * 1024 + k0 + sc;
            async_copy16(gb, (char*)Bs + (wv * 4 + i) * 1024);
        }
        __syncthreads();
#pragma unroll
        for (int kt = 0; kt < 2; ++kt) {
            short8 af[4], bf[4];
#pragma unroll
            for (int mt2 = 0; mt2 < 4; ++mt2) {
                int row = wm * 64 + mt2 * 16 + l15;
                int kc = kt * 4 + quad;
                af[mt2] = *(const short8*)((const char*)As + row * 128 + ((kc ^ (row & 7)) << 4));
            }
#pragma unroll
            for (int nt2 = 0; nt2 < 4; ++nt2) {
                int rown = wn * 64 + nt2 * 16 + l15;
                int kc = kt * 4 + quad;
                bf[nt2] = *(const short8*)((const char*)Bs + rown * 128 + ((kc ^ (rown & 7)) << 4));
            }
#pragma unroll
            for (int mt2 = 0; mt2 < 4; ++mt2)
#pragma unroll
                for (int nt2 = 0; nt2 < 4; ++nt2)
                    acc[mt2][nt2] = __builtin_amdgcn_mfma_f32_16x16x32_bf16(
                        af[mt2], bf[nt2], acc[mt2][nt2], 0, 0, 0);
        }
    }

    // epilogue: C/D layout col=lane&15, row=quad*4+reg.
#pragma unroll
    for (int mt2 = 0; mt2 < 4; ++mt2) {
        int mbase = m0 + wm * 64 + mt2 * 16 + quad * 4;
        int b_ = mbase >> 10, t_ = mbase & 1023;
#pragma unroll
        for (int nt2 = 0; nt2 < 4; ++nt2) {
            int n = n0 + wn * 64 + nt2 * 16 + l15;
            int gate = n >> 10, u = n & 1023;
            float bv = bias[n];
            s16x4 pk;
            pk[0] = (short)f2bf(acc[mt2][nt2][0] + bv);
            pk[1] = (short)f2bf(acc[mt2][nt2][1] + bv);
            pk[2] = (short)f2bf(acc[mt2][nt2][2] + bv);
            pk[3] = (short)f2bf(acc[mt2][nt2][3] + bv);
            // gT[t_>>3][b_][gate][u][t_&7]
            size_t off = ((((size_t)(t_ >> 3) * 32 + (size_t)b_) * 4 + (size_t)gate) << 13)
                         + ((size_t)u << 3) + (size_t)(t_ & 7);
            *(s16x4*)(gT + off) = pk;
        }
    }
}

// ---------------- pass 1: boundary c-chain ----------------
// Sequential c-recurrence over t=0..895 (ranges 0..6 of pass 2), reading only
// gates 0,1. Emits c at t=127,255,...,895 -> cB[7][B][U] f32 (1 MB).
// Producer/consumer: wave0 issues 2 global_load_lds per 8-t group into an
// 8-slot x 2KB LDS ring (vmcnt counts only copies -> exact counted waits:
// steady state vmcnt(12) = 6 groups in flight). wave1 runs the chain.
__global__ __launch_bounds__(128) void scan_c_kernel(const unsigned short* __restrict__ gT,
                                                     const float* __restrict__ c0,
                                                     const float* __restrict__ Vf,
                                                     float* __restrict__ cB) {
    __shared__ __align__(16) unsigned short sbuf[8 * 1024];   // 8 slots x 2048 B

    const int NT = 112;                       // t-blocks 0..111 (t<896)
    const int D = 8;
    int blk = blockIdx.x;                     // 0..511
    int b = blk >> 4;
    int u0 = (blk & 15) << 6;
    int tid = threadIdx.x;
    int wv = tid >> 6;
    int lane = tid & 63;

    if (wv == 0) {
        // producer: gates 0,1 (a1, a2)
        size_t base = ((size_t)b * 4) * 8192 + ((size_t)(u0 + lane) << 3);
        const unsigned short* pg0 = gT + base;
        const unsigned short* pg1 = pg0 + 8192;
#pragma unroll
        for (int g = 0; g < D - 1; ++g) {
            char* ld = (char*)sbuf + (g & 7) * 2048;
            size_t o = (size_t)g << 20;                   // t-block stride = 1M elems
            async_copy16(pg0 + o, ld);
            async_copy16(pg1 + o, ld + 1024);
        }
        for (int j = 0; j < NT; ++j) {
            if (j < NT - (D - 2)) {
                asm volatile("s_waitcnt vmcnt(12)" ::: "memory");
            } else {
                asm volatile("s_waitcnt vmcnt(0)" ::: "memory");
            }
            __builtin_amdgcn_s_barrier();
            int g = j + D - 1;
            if (g < NT) {
                char* ld = (char*)sbuf + (g & 7) * 2048;
                size_t o = (size_t)g << 20;
                async_copy16(pg0 + o, ld);
                async_copy16(pg1 + o, ld + 1024);
            }
        }
    } else {
        int u = u0 + lane;
        float c = c0[(b << 10) + u];
        float vf = Vf[u];
        const unsigned short* ls = sbuf + (size_t)lane * 8;
        for (int j = 0; j < NT; ++j) {
            __builtin_amdgcn_s_barrier();
            asm volatile("" ::: "memory");
            int so = (j & 7) * 1024;                      // slot offset in shorts
            short8 a1 = *(const short8*)(ls + so);
            short8 a2 = *(const short8*)(ls + so + 512);
#pragma unroll
            for (int i = 0; i < 8; ++i) {
                float x1 = bf2f((unsigned short)a1[i]);
                float x2 = bf2f((unsigned short)a2[i]);
                float f  = sigmoid_f(x1 + vf * c);
                c = fmaf(f, c - x2, x2);                  // same op sequence as before
            }
            if ((j & 15) == 15) {                         // j=15,31,...,111 -> idx 0..6
                cB[((size_t)(j >> 4) << 15) + (size_t)(b << 10) + u] = c;
            }
        }
    }
}

// ---------------- pass 2: parallel recompute + h ----------------
// 8 t-ranges x 128 t each, per (b,u): 262144 threads (16 waves/CU -> latency
// hidden by TLP). Each thread restarts the EXACT f32 c-chain from its range
// boundary (bitwise-identical op sequence -> output matches single-pass), and
// computes r/h. Reads all 4 gates (256 MB) + cB, writes h (128 MB).
__global__ __launch_bounds__(256) void scan_h_kernel(const unsigned short* __restrict__ gT,
                                                     const float* __restrict__ c0,
                                                     const float* __restrict__ cB,
                                                     const float* __restrict__ Vr,
                                                     const float* __restrict__ Vf,
                                                     float* __restrict__ h) {
    int idx = blockIdx.x * 256 + threadIdx.x;   // 0..262143
    int u = idx & 1023;
    int rb = idx >> 10;
    int r = rb >> 5, b = rb & 31;
    float vf = Vf[u], vr = Vr[u];
    float c = (r == 0) ? c0[(b << 10) + u]
                       : cB[((size_t)(r - 1) << 15) + (size_t)(b << 10) + u];
    const unsigned short* base = gT + ((size_t)b * 4) * 8192 + ((size_t)u << 3);
    float* hb = h + ((size_t)b << 20) + u;
    int tb0 = r << 4;

    const unsigned short* p0 = base + ((size_t)tb0 << 20);
    short8 n1 = *(const short8*)(p0);
    short8 n2 = *(const short8*)(p0 + 8192);
    short8 n3 = *(const short8*)(p0 + 16384);
    short8 n4 = *(const short8*)(p0 + 24576);
    for (int j = 0; j < 16; ++j) {
        short8 a1 = n1, a2 = n2, a3 = n3, a4 = n4;
        if (j < 15) {                                     // prefetch next t-block
            const unsigned short* q = base + ((size_t)(tb0 + j + 1) << 20);
            n1 = *(const short8*)(q);
            n2 = *(const short8*)(q + 8192);
            n3 = *(const short8*)(q + 16384);
            n4 = *(const short8*)(q + 24576);
        }
        int t0 = (tb0 + j) * 8;
#pragma unroll
        for (int i = 0; i < 8; ++i) {
            float x1 = bf2f((unsigned short)a1[i]);
            float x2 = bf2f((unsigned short)a2[i]);
            float x3 = bf2f((unsigned short)a3[i]);
            float x4 = bf2f((unsigned short)a4[i]);
            float f  = sigmoid_f(x1 + vf * c);
            float cp = c;
            c = fmaf(f, c - x2, x2);                      // c_t
            float rr = sigmoid_f(x3 + vr * cp);           // uses c_{t-1}
            float hv = fmaf(rr, c - x4, x4);
            hb[(size_t)(t0 + i) << 10] = hv;
        }
    }
}

extern "C" void kernel_launch(void* const* d_in, const int* in_sizes, int n_in,
                              void* d_out, int out_size, void* d_ws, size_t ws_size,
                              hipStream_t stream) {
    const float* x  = (const float*)d_in[0];
    // d_in[1] = h0 (unused by reference)
    const float* c0 = (const float*)d_in[2];
    const float* W  = (const float*)d_in[3];
    const float* b  = (const float*)d_in[4];
    const float* Vr = (const float*)d_in[5];
    const float* Vf = (const float*)d_in[6];
    float* h = (float*)d_out;

    char* ws = (char*)d_ws;
    unsigned short* xb = (unsigned short*)ws;                         // 64 MB
    unsigned short* wt = (unsigned short*)(ws + (size_t)67108864);    // 8 MB
    unsigned short* gT = (unsigned short*)(ws + (size_t)75497472);    // 256 MB
    // cB aliases the xb region: xb is dead once gemm_kernel has completed
    // (stream-ordered), so total workspace footprint is unchanged vs round 3.
    float* cB = (float*)ws;                                           // 1 MB

    cvt_x_kernel<<<16384, 256, 0, stream>>>(x, xb);
    cvt_w_kernel<<<1024, 256, 0, stream>>>(W, wt);
    gemm_kernel<<<8192, 256, 0, stream>>>(xb, wt, b, gT);
    scan_c_kernel<<<512, 128, 0, stream>>>(gT, c0, Vf, cB);
    scan_h_kernel<<<1024, 256, 0, stream>>>(gT, c0, cB, Vr, Vf, h);
}

// Round 6
// 579.397 us; speedup vs baseline: 1.0058x; 1.0058x over previous
//
#include <hip/hip_runtime.h>
#include <cstdint>
#include <cstddef>

typedef short short8 __attribute__((ext_vector_type(8)));
typedef short s16x4 __attribute__((ext_vector_type(4)));
typedef float f32x4 __attribute__((ext_vector_type(4)));

typedef const __attribute__((address_space(1))) void* gas_ptr;
typedef __attribute__((address_space(3))) void* las_ptr;

__device__ __forceinline__ unsigned short f2bf(float f) {
    unsigned int u = __float_as_uint(f);
    u += 0x7fffu + ((u >> 16) & 1u);          // RNE (finite inputs)
    return (unsigned short)(u >> 16);
}
__device__ __forceinline__ float bf2f(unsigned short s) {
    return __uint_as_float(((unsigned int)s) << 16);
}
__device__ __forceinline__ float sigmoid_f(float z) {
    return __builtin_amdgcn_rcpf(1.0f + __expf(-z));
}
__device__ __forceinline__ void async_copy16(const void* gp, void* lp) {
    __builtin_amdgcn_global_load_lds((gas_ptr)gp, (las_ptr)lp, 16, 0, 0);
}

// ---------------- converters ----------------
// x: [32768,1024] f32 -> bf16, same layout. 8 elems/thread.
__global__ __launch_bounds__(256) void cvt_x_kernel(const float* __restrict__ in,
                                                    unsigned short* __restrict__ out) {
    size_t i = ((size_t)blockIdx.x * 256 + threadIdx.x) * 8;
    float4 v0 = *(const float4*)(in + i);
    float4 v1 = *(const float4*)(in + i + 4);
    short8 o;
    o[0]=(short)f2bf(v0.x); o[1]=(short)f2bf(v0.y); o[2]=(short)f2bf(v0.z); o[3]=(short)f2bf(v0.w);
    o[4]=(short)f2bf(v1.x); o[5]=(short)f2bf(v1.y); o[6]=(short)f2bf(v1.z); o[7]=(short)f2bf(v1.w);
    *(short8*)(out + i) = o;
}

// W: [1024,4096] f32 -> W_T bf16 [4096,1024]. 64x64 LDS tiles.
__global__ __launch_bounds__(256) void cvt_w_kernel(const float* __restrict__ W,
                                                    unsigned short* __restrict__ Wt) {
    __shared__ unsigned short tile[64][65];
    int bk = blockIdx.x >> 6, bn = blockIdx.x & 63;
    int k0 = bk * 64, n0 = bn * 64;
    int t = threadIdx.x;
    int cr = t >> 6;          // 0..3
    int cc = t & 63;          // 0..63
#pragma unroll
    for (int i = 0; i < 16; ++i) {
        int row = i * 4 + cr;
        tile[row][cc] = f2bf(W[(size_t)(k0 + row) * 4096 + n0 + cc]);
    }
    __syncthreads();
#pragma unroll
    for (int i = 0; i < 16; ++i) {
        int nrow = i * 4 + cr;
        Wt[(size_t)(n0 + nrow) * 1024 + k0 + cc] = tile[cc][nrow];
    }
}

// ---------------- GEMM ----------------
// (unchanged — 251-260 us, MfmaUtil 52%)
// Output: gT bf16 TIME-MAJOR blocked [T/8][b][gate][u][8].
__global__ __launch_bounds__(256, 2) void gemm_kernel(const unsigned short* __restrict__ A,
                                                      const unsigned short* __restrict__ Bt,
                                                      const float* __restrict__ bias,
                                                      unsigned short* __restrict__ gT) {
    __shared__ __align__(16) unsigned short As[128 * 64];
    __shared__ __align__(16) unsigned short Bs[128 * 64];

    // band swizzle: 8 m-tiles x 32 n-tiles per band, n fastest
    int bid = blockIdx.x;
    int band = bid >> 8;
    int r = bid & 255;
    int mt = band * 8 + (r >> 5);
    int nt = r & 31;
    int m0 = mt * 128, n0 = nt * 128;

    int tidx = threadIdx.x;
    int lane = tidx & 63, wv = tidx >> 6;
    int wm = wv >> 1, wn = wv & 1;
    int l15 = lane & 15, quad = lane >> 4;

    f32x4 acc[4][4] = {};

    for (int k0 = 0; k0 < 1024; k0 += 64) {
        __syncthreads();
#pragma unroll
        for (int i = 0; i < 4; ++i) {
            int ci = (wv * 4 + i) * 64 + lane;      // 0..1023
            int row = ci >> 3, cc = ci & 7;
            int sc = (cc ^ (row & 7)) << 3;         // swizzled k-offset (elements)
            const unsigned short* ga = A + (size_t)(m0 + row) * 1024 + k0 + sc;
            async_copy16(ga, (char*)As + (wv * 4 + i) * 1024);
            const unsigned short* gb = Bt + (size_t)(n0 + row) * 1024 + k0 + sc;
            async_copy16(gb, (char*)Bs + (wv * 4 + i) * 1024);
        }
        __syncthreads();
#pragma unroll
        for (int kt = 0; kt < 2; ++kt) {
            short8 af[4], bf[4];
#pragma unroll
            for (int mt2 = 0; mt2 < 4; ++mt2) {
                int row = wm * 64 + mt2 * 16 + l15;
                int kc = kt * 4 + quad;
                af[mt2] = *(const short8*)((const char*)As + row * 128 + ((kc ^ (row & 7)) << 4));
            }
#pragma unroll
            for (int nt2 = 0; nt2 < 4; ++nt2) {
                int rown = wn * 64 + nt2 * 16 + l15;
                int kc = kt * 4 + quad;
                bf[nt2] = *(const short8*)((const char*)Bs + rown * 128 + ((kc ^ (rown & 7)) << 4));
            }
#pragma unroll
            for (int mt2 = 0; mt2 < 4; ++mt2)
#pragma unroll
                for (int nt2 = 0; nt2 < 4; ++nt2)
                    acc[mt2][nt2] = __builtin_amdgcn_mfma_f32_16x16x32_bf16(
                        af[mt2], bf[nt2], acc[mt2][nt2], 0, 0, 0);
        }
    }

    // epilogue: C/D layout col=lane&15, row=quad*4+reg.
#pragma unroll
    for (int mt2 = 0; mt2 < 4; ++mt2) {
        int mbase = m0 + wm * 64 + mt2 * 16 + quad * 4;
        int b_ = mbase >> 10, t_ = mbase & 1023;
#pragma unroll
        for (int nt2 = 0; nt2 < 4; ++nt2) {
            int n = n0 + wn * 64 + nt2 * 16 + l15;
            int gate = n >> 10, u = n & 1023;
            float bv = bias[n];
            s16x4 pk;
            pk[0] = (short)f2bf(acc[mt2][nt2][0] + bv);
            pk[1] = (short)f2bf(acc[mt2][nt2][1] + bv);
            pk[2] = (short)f2bf(acc[mt2][nt2][2] + bv);
            pk[3] = (short)f2bf(acc[mt2][nt2][3] + bv);
            // gT[t_>>3][b_][gate][u][t_&7]
            size_t off = ((((size_t)(t_ >> 3) * 32 + (size_t)b_) * 4 + (size_t)gate) << 13)
                         + ((size_t)u << 3) + (size_t)(t_ & 7);
            *(s16x4*)(gT + off) = pk;
        }
    }
}

// ---------------- pass 1: boundary c-chain, TLP-staged ----------------
// Serial c-recurrence over t=0..895 reading gates 0,1; emits c at t=127..895
// into cB[7][B][U] f32. Block = 512 thr (8 waves), 512 blocks = 16 waves/CU.
// Waves 1-7 bulk-stage 128-t chunks (2 gates x 16 t-blocks x 64 u = 32 KB) into
// a double-buffered LDS ring via global_load_lds (linear dest = base + lane*16);
// wave 0 runs the exact f32 chain from LDS. One __syncthreads (full drain) per
// 128 t — 16x lower sync/drain frequency than r5's per-8-t barrier, and load
// issue is 7-wave parallel (TLP, not ILP, hides HBM latency).
__global__ __launch_bounds__(512) void scan_c_kernel(const unsigned short* __restrict__ gT,
                                                     const float* __restrict__ c0,
                                                     const float* __restrict__ Vf,
                                                     float* __restrict__ cB) {
    // [dbuf(2)][gate(2)][tbi(16)][u(64)][t(8)] bf16 = 64 KB
    __shared__ __align__(16) unsigned short sbuf[2 * 2 * 16 * 512];

    const int NCH = 7;                        // chunks of 16 t-blocks (t<896)
    int blk = blockIdx.x;                     // 0..511
    int b = blk >> 4;
    int u0 = (blk & 15) << 6;
    int tid = threadIdx.x;
    int wv = tid >> 6;
    int lane = tid & 63;

    // stage chunk k into buffer (k&1): waves 1..7 split the 32 planes
    // plane p: gate = p>>4, tbi = p&15.
    // gT offset: tb<<20 + b*32768 + gate*8192 + u*8 (elements)
    size_t gbase = (size_t)b * 32768 + ((size_t)(u0 + lane) << 3);

    if (wv >= 1) {
        // prologue: chunk 0 -> buf 0
        for (int p = wv - 1; p < 32; p += 7) {
            int gate = p >> 4, tbi = p & 15;
            const unsigned short* src = gT + (((size_t)tbi) << 20) + gbase + gate * 8192;
            char* dst = (char*)sbuf + gate * 16384 + tbi * 1024 + lane * 16;
            async_copy16(src, dst);
        }
    }
    __syncthreads();

    float c = 0.0f, vf = 0.0f;
    if (wv == 0) {
        int u = u0 + lane;
        c = c0[(b << 10) + u];
        vf = Vf[u];
    }

    for (int k = 0; k < NCH; ++k) {
        if (wv >= 1) {
            if (k + 1 < NCH) {
                int nb = (k + 1) & 1;
                for (int p = wv - 1; p < 32; p += 7) {
                    int gate = p >> 4, tbi = p & 15;
                    const unsigned short* src =
                        gT + (((size_t)((k + 1) * 16 + tbi)) << 20) + gbase + gate * 8192;
                    char* dst = (char*)sbuf + nb * 32768 + gate * 16384 + tbi * 1024 + lane * 16;
                    async_copy16(src, dst);
                }
            }
        } else {
            const unsigned short* ls = sbuf + (k & 1) * 16384 + (size_t)lane * 8;
#pragma unroll
            for (int tbi = 0; tbi < 16; ++tbi) {
                short8 a1 = *(const short8*)(ls + tbi * 512);
                short8 a2 = *(const short8*)(ls + 8192 + tbi * 512);
#pragma unroll
                for (int i = 0; i < 8; ++i) {
                    float x1 = bf2f((unsigned short)a1[i]);
                    float x2 = bf2f((unsigned short)a2[i]);
                    float f  = sigmoid_f(x1 + vf * c);
                    c = fmaf(f, c - x2, x2);          // exact same op sequence
                }
            }
            // end of chunk k = t-block 16k+15 = t 128k+127 -> cB[k]
            cB[((size_t)k << 15) + (size_t)(b << 10) + (size_t)(u0 + lane)] = c;
        }
        __syncthreads();
    }
}

// ---------------- pass 2: parallel recompute + h ----------------
// (unchanged from r5) 8 t-ranges x 128 t, 262144 threads (16 waves/CU).
// Exact f32 c-chain restart from boundary; reads 4 gates + cB, writes h.
__global__ __launch_bounds__(256) void scan_h_kernel(const unsigned short* __restrict__ gT,
                                                     const float* __restrict__ c0,
                                                     const float* __restrict__ cB,
                                                     const float* __restrict__ Vr,
                                                     const float* __restrict__ Vf,
                                                     float* __restrict__ h) {
    int idx = blockIdx.x * 256 + threadIdx.x;   // 0..262143
    int u = idx & 1023;
    int rb = idx >> 10;
    int r = rb >> 5, b = rb & 31;
    float vf = Vf[u], vr = Vr[u];
    float c = (r == 0) ? c0[(b << 10) + u]
                       : cB[((size_t)(r - 1) << 15) + (size_t)(b << 10) + u];
    const unsigned short* base = gT + ((size_t)b * 4) * 8192 + ((size_t)u << 3);
    float* hb = h + ((size_t)b << 20) + u;
    int tb0 = r << 4;

    const unsigned short* p0 = base + ((size_t)tb0 << 20);
    short8 n1 = *(const short8*)(p0);
    short8 n2 = *(const short8*)(p0 + 8192);
    short8 n3 = *(const short8*)(p0 + 16384);
    short8 n4 = *(const short8*)(p0 + 24576);
    for (int j = 0; j < 16; ++j) {
        short8 a1 = n1, a2 = n2, a3 = n3, a4 = n4;
        if (j < 15) {                                     // prefetch next t-block
            const unsigned short* q = base + ((size_t)(tb0 + j + 1) << 20);
            n1 = *(const short8*)(q);
            n2 = *(const short8*)(q + 8192);
            n3 = *(const short8*)(q + 16384);
            n4 = *(const short8*)(q + 24576);
        }
        int t0 = (tb0 + j) * 8;
#pragma unroll
        for (int i = 0; i < 8; ++i) {
            float x1 = bf2f((unsigned short)a1[i]);
            float x2 = bf2f((unsigned short)a2[i]);
            float x3 = bf2f((unsigned short)a3[i]);
            float x4 = bf2f((unsigned short)a4[i]);
            float f  = sigmoid_f(x1 + vf * c);
            float cp = c;
            c = fmaf(f, c - x2, x2);                      // c_t
            float rr = sigmoid_f(x3 + vr * cp);           // uses c_{t-1}
            float hv = fmaf(rr, c - x4, x4);
            hb[(size_t)(t0 + i) << 10] = hv;
        }
    }
}

extern "C" void kernel_launch(void* const* d_in, const int* in_sizes, int n_in,
                              void* d_out, int out_size, void* d_ws, size_t ws_size,
                              hipStream_t stream) {
    const float* x  = (const float*)d_in[0];
    // d_in[1] = h0 (unused by reference)
    const float* c0 = (const float*)d_in[2];
    const float* W  = (const float*)d_in[3];
    const float* b  = (const float*)d_in[4];
    const float* Vr = (const float*)d_in[5];
    const float* Vf = (const float*)d_in[6];
    float* h = (float*)d_out;

    char* ws = (char*)d_ws;
    unsigned short* xb = (unsigned short*)ws;                         // 64 MB
    unsigned short* wt = (unsigned short*)(ws + (size_t)67108864);    // 8 MB
    unsigned short* gT = (unsigned short*)(ws + (size_t)75497472);    // 256 MB
    // cB aliases the xb region: xb is dead once gemm_kernel has completed
    // (stream-ordered), so workspace footprint is unchanged.
    float* cB = (float*)ws;                                           // 1 MB

    cvt_x_kernel<<<16384, 256, 0, stream>>>(x, xb);
    cvt_w_kernel<<<1024, 256, 0, stream>>>(W, wt);
    gemm_kernel<<<8192, 256, 0, stream>>>(xb, wt, b, gT);
    scan_c_kernel<<<512, 512, 0, stream>>>(gT, c0, Vf, cB);
    scan_h_kernel<<<1024, 256, 0, stream>>>(gT, c0, cB, Vr, Vf, h);
}

// Round 7
// 562.568 us; speedup vs baseline: 1.0359x; 1.0299x over previous
//
#include <hip/hip_runtime.h>
#include <cstdint>
#include <cstddef>

typedef short short8 __attribute__((ext_vector_type(8)));
typedef short s16x4 __attribute__((ext_vector_type(4)));
typedef float f32x4 __attribute__((ext_vector_type(4)));

typedef const __attribute__((address_space(1))) void* gas_ptr;
typedef __attribute__((address_space(3))) void* las_ptr;

__device__ __forceinline__ unsigned short f2bf(float f) {
    unsigned int u = __float_as_uint(f);
    u += 0x7fffu + ((u >> 16) & 1u);          // RNE (finite inputs)
    return (unsigned short)(u >> 16);
}
__device__ __forceinline__ float bf2f(unsigned short s) {
    return __uint_as_float(((unsigned int)s) << 16);
}
__device__ __forceinline__ float sigmoid_f(float z) {
    return __builtin_amdgcn_rcpf(1.0f + __expf(-z));
}
__device__ __forceinline__ void async_copy16(const void* gp, void* lp) {
    __builtin_amdgcn_global_load_lds((gas_ptr)gp, (las_ptr)lp, 16, 0, 0);
}

// ---------------- converters ----------------
// x: [32768,1024] f32 -> bf16, same layout. 8 elems/thread.
__global__ __launch_bounds__(256) void cvt_x_kernel(const float* __restrict__ in,
                                                    unsigned short* __restrict__ out) {
    size_t i = ((size_t)blockIdx.x * 256 + threadIdx.x) * 8;
    float4 v0 = *(const float4*)(in + i);
    float4 v1 = *(const float4*)(in + i + 4);
    short8 o;
    o[0]=(short)f2bf(v0.x); o[1]=(short)f2bf(v0.y); o[2]=(short)f2bf(v0.z); o[3]=(short)f2bf(v0.w);
    o[4]=(short)f2bf(v1.x); o[5]=(short)f2bf(v1.y); o[6]=(short)f2bf(v1.z); o[7]=(short)f2bf(v1.w);
    *(short8*)(out + i) = o;
}

// W: [1024,4096] f32 -> W_T bf16 [4096,1024]. 64x64 LDS tiles.
__global__ __launch_bounds__(256) void cvt_w_kernel(const float* __restrict__ W,
                                                    unsigned short* __restrict__ Wt) {
    __shared__ unsigned short tile[64][65];
    int bk = blockIdx.x >> 6, bn = blockIdx.x & 63;
    int k0 = bk * 64, n0 = bn * 64;
    int t = threadIdx.x;
    int cr = t >> 6;          // 0..3
    int cc = t & 63;          // 0..63
#pragma unroll
    for (int i = 0; i < 16; ++i) {
        int row = i * 4 + cr;
        tile[row][cc] = f2bf(W[(size_t)(k0 + row) * 4096 + n0 + cc]);
    }
    __syncthreads();
#pragma unroll
    for (int i = 0; i < 16; ++i) {
        int nrow = i * 4 + cr;
        Wt[(size_t)(n0 + nrow) * 1024 + k0 + cc] = tile[cc][nrow];
    }
}

// ---------------- GEMM ----------------
// (unchanged — 251-260 us, MfmaUtil 52%)
// Output: gT bf16 TIME-MAJOR blocked [T/8][b][gate][u][8].
__global__ __launch_bounds__(256, 2) void gemm_kernel(const unsigned short* __restrict__ A,
                                                      const unsigned short* __restrict__ Bt,
                                                      const float* __restrict__ bias,
                                                      unsigned short* __restrict__ gT) {
    __shared__ __align__(16) unsigned short As[128 * 64];
    __shared__ __align__(16) unsigned short Bs[128 * 64];

    // band swizzle: 8 m-tiles x 32 n-tiles per band, n fastest
    int bid = blockIdx.x;
    int band = bid >> 8;
    int r = bid & 255;
    int mt = band * 8 + (r >> 5);
    int nt = r & 31;
    int m0 = mt * 128, n0 = nt * 128;

    int tidx = threadIdx.x;
    int lane = tidx & 63, wv = tidx >> 6;
    int wm = wv >> 1, wn = wv & 1;
    int l15 = lane & 15, quad = lane >> 4;

    f32x4 acc[4][4] = {};

    for (int k0 = 0; k0 < 1024; k0 += 64) {
        __syncthreads();
#pragma unroll
        for (int i = 0; i < 4; ++i) {
            int ci = (wv * 4 + i) * 64 + lane;      // 0..1023
            int row = ci >> 3, cc = ci & 7;
            int sc = (cc ^ (row & 7)) << 3;         // swizzled k-offset (elements)
            const unsigned short* ga = A + (size_t)(m0 + row) * 1024 + k0 + sc;
            async_copy16(ga, (char*)As + (wv * 4 + i) * 1024);
            const unsigned short* gb = Bt + (size_t)(n0 + row) * 1024 + k0 + sc;
            async_copy16(gb, (char*)Bs + (wv * 4 + i) * 1024);
        }
        __syncthreads();
#pragma unroll
        for (int kt = 0; kt < 2; ++kt) {
            short8 af[4], bf[4];
#pragma unroll
            for (int mt2 = 0; mt2 < 4; ++mt2) {
                int row = wm * 64 + mt2 * 16 + l15;
                int kc = kt * 4 + quad;
                af[mt2] = *(const short8*)((const char*)As + row * 128 + ((kc ^ (row & 7)) << 4));
            }
#pragma unroll
            for (int nt2 = 0; nt2 < 4; ++nt2) {
                int rown = wn * 64 + nt2 * 16 + l15;
                int kc = kt * 4 + quad;
                bf[nt2] = *(const short8*)((const char*)Bs + rown * 128 + ((kc ^ (rown & 7)) << 4));
            }
#pragma unroll
            for (int mt2 = 0; mt2 < 4; ++mt2)
#pragma unroll
                for (int nt2 = 0; nt2 < 4; ++nt2)
                    acc[mt2][nt2] = __builtin_amdgcn_mfma_f32_16x16x32_bf16(
                        af[mt2], bf[nt2], acc[mt2][nt2], 0, 0, 0);
        }
    }

    // epilogue: C/D layout col=lane&15, row=quad*4+reg.
#pragma unroll
    for (int mt2 = 0; mt2 < 4; ++mt2) {
        int mbase = m0 + wm * 64 + mt2 * 16 + quad * 4;
        int b_ = mbase >> 10, t_ = mbase & 1023;
#pragma unroll
        for (int nt2 = 0; nt2 < 4; ++nt2) {
            int n = n0 + wn * 64 + nt2 * 16 + l15;
            int gate = n >> 10, u = n & 1023;
            float bv = bias[n];
            s16x4 pk;
            pk[0] = (short)f2bf(acc[mt2][nt2][0] + bv);
            pk[1] = (short)f2bf(acc[mt2][nt2][1] + bv);
            pk[2] = (short)f2bf(acc[mt2][nt2][2] + bv);
            pk[3] = (short)f2bf(acc[mt2][nt2][3] + bv);
            // gT[t_>>3][b_][gate][u][t_&7]
            size_t off = ((((size_t)(t_ >> 3) * 32 + (size_t)b_) * 4 + (size_t)gate) << 13)
                         + ((size_t)u << 3) + (size_t)(t_ & 7);
            *(s16x4*)(gT + off) = pk;
        }
    }
}

// ---------------- fused scan: TLP-staged single pass ----------------
// gT bf16 time-major [T/8][B][4][U][8]; h f32 [B,T,U].
// Block = 512 thr (8 waves), 512 blocks (= 2 blocks/CU, 16 waves/CU).
// Waves 1-7 bulk-stage 64-t chunks of ALL 4 gates (32 KB) into a double-
// buffered LDS ring via global_load_lds (linear dest = base + lane*16);
// wave 0 runs the exact f32 recurrence from LDS and writes h.
// One __syncthreads (vmcnt drain) per 64 t -> 16 total. Load issue is
// 7-wave parallel: TLP hides HBM latency, not per-wave ILP.
__global__ __launch_bounds__(512, 4) void scan_kernel(const unsigned short* __restrict__ gT,
                                                      const float* __restrict__ c0,
                                                      const float* __restrict__ Vr,
                                                      const float* __restrict__ Vf,
                                                      float* __restrict__ h) {
    // [dbuf 2][gate 4][tbi 8][u 64][t 8] bf16 = 2 x 32 KB
    __shared__ __align__(16) unsigned short sbuf[2 * 4 * 8 * 512];

    const int NCH = 16;                       // 16 chunks x 8 t-blocks = 1024 t
    int blk = blockIdx.x;                     // 0..511
    int b = blk >> 4;
    int u0 = (blk & 15) << 6;
    int tid = threadIdx.x;
    int wv = tid >> 6;
    int lane = tid & 63;

    // gT element offset: tb<<20 + b*32768 + gate*8192 + u*8
    size_t gbase = (size_t)b * 32768 + ((size_t)(u0 + lane) << 3);

    if (wv >= 1) {
        // prologue: chunk 0 -> buf 0.  32 planes (4 gates x 8 tbi) / 7 waves.
        for (int p = wv - 1; p < 32; p += 7) {
            int gate = p >> 3, tbi = p & 7;
            const unsigned short* src = gT + ((size_t)tbi << 20) + gbase + gate * 8192;
            char* dst = (char*)sbuf + gate * 8192 + tbi * 1024 + lane * 16;
            async_copy16(src, dst);
        }
    }
    __syncthreads();

    float c = 0.0f, vf = 0.0f, vr = 0.0f;
    float* hb = nullptr;
    if (wv == 0) {
        int u = u0 + lane;
        c = c0[(b << 10) + u];
        vf = Vf[u];
        vr = Vr[u];
        hb = h + ((size_t)b << 20) + u;
    }

    for (int k = 0; k < NCH; ++k) {
        if (wv >= 1) {
            if (k + 1 < NCH) {
                int nb = (k + 1) & 1;
                for (int p = wv - 1; p < 32; p += 7) {
                    int gate = p >> 3, tbi = p & 7;
                    const unsigned short* src =
                        gT + ((size_t)((k + 1) * 8 + tbi) << 20) + gbase + gate * 8192;
                    char* dst = (char*)sbuf + nb * 32768 + gate * 8192 + tbi * 1024 + lane * 16;
                    async_copy16(src, dst);
                }
            }
        } else {
            const unsigned short* ls = sbuf + (k & 1) * 16384 + (size_t)lane * 8;
#pragma unroll
            for (int tbi = 0; tbi < 8; ++tbi) {
                short8 a1 = *(const short8*)(ls + tbi * 512);
                short8 a2 = *(const short8*)(ls + 4096 + tbi * 512);
                short8 a3 = *(const short8*)(ls + 8192 + tbi * 512);
                short8 a4 = *(const short8*)(ls + 12288 + tbi * 512);
                int t0 = (k * 8 + tbi) * 8;
#pragma unroll
                for (int i = 0; i < 8; ++i) {
                    float x1 = bf2f((unsigned short)a1[i]);
                    float x2 = bf2f((unsigned short)a2[i]);
                    float x3 = bf2f((unsigned short)a3[i]);
                    float x4 = bf2f((unsigned short)a4[i]);
                    float f  = sigmoid_f(x1 + vf * c);
                    float cp = c;
                    c = fmaf(f, c - x2, x2);          // c_t  (same op sequence)
                    float rr = sigmoid_f(x3 + vr * cp); // uses c_{t-1}
                    float hv = fmaf(rr, c - x4, x4);
                    hb[(size_t)(t0 + i) << 10] = hv;
                }
            }
        }
        __syncthreads();
    }
}

extern "C" void kernel_launch(void* const* d_in, const int* in_sizes, int n_in,
                              void* d_out, int out_size, void* d_ws, size_t ws_size,
                              hipStream_t stream) {
    const float* x  = (const float*)d_in[0];
    // d_in[1] = h0 (unused by reference)
    const float* c0 = (const float*)d_in[2];
    const float* W  = (const float*)d_in[3];
    const float* b  = (const float*)d_in[4];
    const float* Vr = (const float*)d_in[5];
    const float* Vf = (const float*)d_in[6];
    float* h = (float*)d_out;

    char* ws = (char*)d_ws;
    unsigned short* xb = (unsigned short*)ws;                         // 64 MB
    unsigned short* wt = (unsigned short*)(ws + (size_t)67108864);    // 8 MB
    unsigned short* gT = (unsigned short*)(ws + (size_t)75497472);    // 256 MB

    cvt_x_kernel<<<16384, 256, 0, stream>>>(x, xb);
    cvt_w_kernel<<<1024, 256, 0, stream>>>(W, wt);
    gemm_kernel<<<8192, 256, 0, stream>>>(xb, wt, b, gT);
    scan_kernel<<<512, 512, 0, stream>>>(gT, c0, Vr, Vf, h);
}